// Round 29
// baseline (77.854 us; speedup 1.0000x reference)
//
#include <hip/hip_runtime.h>
#include <cstdint>
#include <cstddef>

#define NB1      16384      // 2^14 bins (fallback path only)
#define L1SHIFT  18
#define K_TOP    1000
#define NCAND    5000
#define NIMG     8
#define NLVL     5
#define NTASK    40
#define NPOST    300
#define NEGF     (-1e9f)
#define NWORDS   79         // ceil(5000/64)
#define NPAD     (NWORDS * 64)
#define NSLOT    23         // per-image slices: 16+4+1+1+1
#define SCAP     2048       // per-slice staged-candidate cap

typedef unsigned long long u64;

struct Ptrs {
    const float* lg[5];
    const float* dl[5];
};

__device__ __forceinline__ unsigned key_of(float f) {
    unsigned u = __float_as_uint(f);
    return (u & 0x80000000u) ? ~u : (u | 0x80000000u);
}

__device__ __forceinline__ void lvl_of_slot(int bx, int& lvl, int& lb, int& gx, int& m) {
    lvl = (bx < 16) ? 0 : (bx < 20) ? 1 : (bx < 21) ? 2 : (bx < 22) ? 3 : 4;
    const int S0[5] = {0, 16, 20, 21, 22};
    const int GX[5] = {16, 4, 1, 1, 1};
    const int MS[5] = {516096, 129024, 32256, 8064, 2016};
    lb = bx - S0[lvl];
    gx = GX[lvl];
    m  = MS[lvl];
}

// ---------------- pass 1: pure stream + fixed-threshold staging (no histogram) ----
__global__ __launch_bounds__(1024) void kStage(Ptrs p,
                                               u64* __restrict__ compS,
                                               unsigned* __restrict__ bcnt) {
    int lvl, lb, gx, m;
    lvl_of_slot(blockIdx.x, lvl, lb, gx, m);
    int img = blockIdx.y;
    size_t slice = (size_t)img * NSLOT + blockIdx.x;
    const float* lg = p.lg[lvl];
    const float TF5[5] = {2.65f, 2.2f, 1.6f, 0.9f, -0.35f};
    float Tf = TF5[lvl];
    __shared__ unsigned lcnt;
    int tid = threadIdx.x, lane = tid & 63;
    if (tid == 0) lcnt = 0u;
    __syncthreads();
    int m4 = m >> 2;
    int chunk4 = (m4 + gx - 1) / gx;
    int start4 = lb * chunk4;
    int end4   = min(start4 + chunk4, m4);
    const float4* src = (const float4*)(lg + (size_t)img * m);
    u64 below = (1ULL << lane) - 1ULL;
    for (int ib = start4; ib < end4; ib += 1024) {
        int i = ib + tid;
        bool inb = (i < end4);
        float4 v = inb ? src[i] : make_float4(0.f, 0.f, 0.f, 0.f);
        int j = i * 4;
        bool p0 = inb && (v.x > Tf);
        bool p1 = inb && (v.y > Tf);
        bool p2 = inb && (v.z > Tf);
        bool p3 = inb && (v.w > Tf);
        u64 m0 = __ballot(p0);
        u64 m1 = __ballot(p1);
        u64 m2 = __ballot(p2);
        u64 m3 = __ballot(p3);
        unsigned n0 = (unsigned)__popcll(m0), n1 = (unsigned)__popcll(m1);
        unsigned n2 = (unsigned)__popcll(m2), n3 = (unsigned)__popcll(m3);
        unsigned ntot = n0 + n1 + n2 + n3;
        unsigned base = 0;
        if (lane == 0 && ntot) base = atomicAdd(&lcnt, ntot);
        base = (unsigned)__shfl((int)base, 0, 64);
        if (p0) { unsigned q = base + (unsigned)__popcll(m0 & below);
                  if (q < SCAP) compS[slice * SCAP + q] = ((u64)key_of(v.x) << 32) | (unsigned)(~(unsigned)(j)); }
        if (p1) { unsigned q = base + n0 + (unsigned)__popcll(m1 & below);
                  if (q < SCAP) compS[slice * SCAP + q] = ((u64)key_of(v.y) << 32) | (unsigned)(~(unsigned)(j + 1)); }
        if (p2) { unsigned q = base + n0 + n1 + (unsigned)__popcll(m2 & below);
                  if (q < SCAP) compS[slice * SCAP + q] = ((u64)key_of(v.z) << 32) | (unsigned)(~(unsigned)(j + 2)); }
        if (p3) { unsigned q = base + n0 + n1 + n2 + (unsigned)__popcll(m3 & below);
                  if (q < SCAP) compS[slice * SCAP + q] = ((u64)key_of(v.w) << 32) | (unsigned)(~(unsigned)(j + 3)); }
    }
    __syncthreads();
    if (tid == 0) bcnt[slice] = lcnt;            // RAW count (cap checked later)
}

// ---------------- pass 2: count-verified gather + register bitonic, decode ------
// Fallback histogram lives in GLOBAL scratch (histFB): the fallback never fires
// in practice, so no LDS is spent on it (keeps hot-path LDS at ~27 KB).
__global__ __launch_bounds__(1024) void kSortSelect(
        Ptrs p,
        const u64* __restrict__ compS,
        const unsigned* __restrict__ bcnt,
        unsigned* __restrict__ histFB,
        float* __restrict__ cscore,
        float4* __restrict__ cbox,
        float4* __restrict__ cobox,
        unsigned* __restrict__ cog,
        unsigned* __restrict__ vcnt) {
    int task = blockIdx.x;
    int img = task / NLVL, lvl = task % NLVL;
    int tid = threadIdx.x, lane = tid & 63, wv = tid >> 6;
    const int   MS5[5]    = {516096, 129024, 32256, 8064, 2016};
    const int   GW[5]     = {512, 256, 128, 64, 32};
    const float STRIDEF[5]= {4.f, 8.f, 16.f, 32.f, 64.f};
    const int   SIZEI[5]  = {32, 64, 128, 256, 512};
    const float THI5[5]   = {3.0f, 2.5f, 1.95f, 1.25f, 0.15f};   // sure/bnd split
    __shared__ u64 sure[1024];
    __shared__ u64 bnd[2048];
    __shared__ unsigned sblkF[256];
    __shared__ int tmpF[8];
    __shared__ unsigned cS, cB;
    __shared__ unsigned soff[17];
    __shared__ int wTot[16];
    __shared__ int fbS;
    unsigned KH = key_of(THI5[lvl]);
    if (tid == 0) { cS = 0u; cB = 0u; }
    sure[tid] = 0ULL;
    bnd[tid] = 0ULL; bnd[tid + 1024] = 0ULL;
    if (tid < 17) soff[tid] = 0u;
    if (tid == 0) fbS = 0;
    __syncthreads();
    const int S0[5] = {0, 16, 20, 21, 22};
    const int NS[5] = {16, 4, 1, 1, 1};
    int s0 = S0[lvl], ns = NS[lvl];
    if (tid < ns) {
        unsigned raw = bcnt[(size_t)img * NSLOT + s0 + tid];
        if (raw > SCAP) atomicOr((unsigned*)&fbS, 1u);   // slice capped -> fallback
        soff[tid + 1] = min(raw, (unsigned)SCAP);
    }
    __syncthreads();
    if (tid == 0)
        for (int s = 1; s <= 16; ++s) soff[s] += soff[s - 1];
    __syncthreads();
    int tot = (int)soff[ns];
    u64 below = (1ULL << lane) - 1ULL;
    for (int ib = 0; ib < tot; ib += 1024) {
        int idx = ib + tid;
        bool inb = (idx < tot);
        u64 c = 0ULL;
        if (inb) {
            int s = 0;
            while ((int)soff[s + 1] <= idx) ++s;     // <=16 LDS reads
            c = compS[((size_t)img * NSLOT + s0 + s) * SCAP + (idx - (int)soff[s])];
        }
        bool pS = inb && ((unsigned)(c >> 32) > KH);   // v > Tf_hi
        bool pB = inb && !pS;                          // Tf < v <= Tf_hi
        u64 mS = __ballot(pS);
        u64 mB = __ballot(pB);
        unsigned bS = 0, bB = 0;
        if (lane == 0) {
            if (mS) bS = atomicAdd(&cS, (unsigned)__popcll(mS));
            if (mB) bB = atomicAdd(&cB, (unsigned)__popcll(mB));
        }
        bS = (unsigned)__shfl((int)bS, 0, 64);
        bB = (unsigned)__shfl((int)bB, 0, 64);
        if (pS) { unsigned q = bS + (unsigned)__popcll(mS & below); if (q < 1024u) sure[q] = c; }
        if (pB) { unsigned q = bB + (unsigned)__popcll(mB & below); if (q < 2048u) bnd[q] = c; }
    }
    __syncthreads();
    // ---- exact verification (pure counts) ----
    if (tid == 0) {
        if (cS > 1024u || cB > 2048u || (cS + cB) < (unsigned)K_TOP) fbS = 1;
    }
    __syncthreads();
    // ---- fallback: histogram select over raw logits, hist in GLOBAL scratch ----
    if (fbS) {
        int mm = MS5[lvl];
        int mm4 = mm >> 2;
        const float4* s4 = (const float4*)(p.lg[lvl] + (size_t)img * mm);
        unsigned* h = histFB + (size_t)task * NB1;
        for (int i = tid; i < NB1; i += 1024) h[i] = 0u;
        __syncthreads();
        for (int i = tid; i < mm4; i += 1024) {
            float4 v = s4[i];
            atomicAdd(&h[key_of(v.x) >> L1SHIFT], 1u);
            atomicAdd(&h[key_of(v.y) >> L1SHIFT], 1u);
            atomicAdd(&h[key_of(v.z) >> L1SHIFT], 1u);
            atomicAdd(&h[key_of(v.w) >> L1SHIFT], 1u);
        }
        __syncthreads();
        if (tid < 256) {
            unsigned coarse = 0;
            for (int ii = 0; ii < 64; ++ii) coarse += h[tid * 64 + ii];
            sblkF[tid] = coarse;
        }
        __syncthreads();
        unsigned SSv = 0;
        if (tid < 256) {
            SSv = sblkF[tid];
            for (int d = 1; d < 64; d <<= 1) {
                unsigned o = __shfl_down(SSv, d, 64);
                if (lane < 64 - d) SSv += o;
            }
            unsigned wtot = __shfl(SSv, 0, 64);
            if (lane == 0) tmpF[4 + wv] = (int)wtot;
        }
        __syncthreads();
        if (tid < 256) {
            unsigned add = 0;
            for (int w2 = wv + 1; w2 < 4; ++w2) add += (unsigned)tmpF[4 + w2];
            SSv += add;
            bool pred = (SSv >= (unsigned)K_TOP);
            u64 mk = __ballot(pred);
            if (lane == 0)
                tmpF[wv] = mk ? (wv * 64 + (63 - __builtin_clzll(mk))) : -1;
        }
        __syncthreads();
        int tb = max(max(tmpF[0], tmpF[1]), max(tmpF[2], tmpF[3]));
        __syncthreads();
        if (tid == 0) {
            unsigned above = 0;
            for (int b2 = tb + 1; b2 < 256; ++b2) above += sblkF[b2];
            unsigned rem = (unsigned)K_TOP - above;
            unsigned suf = 0;
            int pfx = tb * 64;
            for (int u2 = 63; u2 >= 0; --u2) {
                suf += h[tb * 64 + u2];
                if (suf >= rem) { pfx = tb * 64 + u2; break; }
            }
            tmpF[0] = pfx;
        }
        __syncthreads();
        unsigned pfx = (unsigned)tmpF[0];
        if (tid == 0) { cS = 0u; cB = 0u; }
        sure[tid] = 0ULL;
        bnd[tid] = 0ULL; bnd[tid + 1024] = 0ULL;
        __syncthreads();
        for (int ib = 0; ib < mm4; ib += 1024) {
            int i = ib + tid;
            bool inb = (i < mm4);
            float4 v = inb ? s4[i] : make_float4(0.f, 0.f, 0.f, 0.f);
            int j = i * 4;
            unsigned kk[4] = { key_of(v.x), key_of(v.y), key_of(v.z), key_of(v.w) };
#pragma unroll
            for (int e = 0; e < 4; ++e) {
                unsigned bin = kk[e] >> L1SHIFT;
                bool pS2 = inb && (bin > pfx);
                bool pB2 = inb && (bin == pfx);
                u64 mS2 = __ballot(pS2);
                u64 mB2 = __ballot(pB2);
                unsigned bS2 = 0, bB2 = 0;
                if (lane == 0) {
                    if (mS2) bS2 = atomicAdd(&cS, (unsigned)__popcll(mS2));
                    if (mB2) bB2 = atomicAdd(&cB, (unsigned)__popcll(mB2));
                }
                bS2 = (unsigned)__shfl((int)bS2, 0, 64);
                bB2 = (unsigned)__shfl((int)bB2, 0, 64);
                u64 cc = ((u64)kk[e] << 32) | (unsigned)(~(unsigned)(j + e));
                if (pS2) { unsigned q = bS2 + (unsigned)__popcll(mS2 & below); if (q < 1024u) sure[q] = cc; }
                if (pB2) { unsigned q = bB2 + (unsigned)__popcll(mB2 & below); if (q < 2048u) bnd[q] = cc; }
            }
        }
        __syncthreads();
    }
    unsigned S = cS;
    unsigned B = cB;
    // register bitonic (desc), 1 elem/thread per array; shfl for j<64, LDS for j>=64
    u64 xs = sure[tid], xb = bnd[tid];
    for (int k = 2; k <= 1024; k <<= 1) {
        for (int j = k >> 1; j > 0; j >>= 1) {
            bool up   = ((tid & k) == 0);
            bool iLow = ((tid & j) == 0);
            u64 ys, yb;
            if (j >= 64) {
                sure[tid] = xs; bnd[tid] = xb;
                __syncthreads();
                ys = sure[tid ^ j]; yb = bnd[tid ^ j];
                __syncthreads();
            } else {
                ys = __shfl_xor(xs, j, 64);
                yb = __shfl_xor(xb, j, 64);
            }
            bool takeMax = (iLow == up);
            xs = takeMax ? ((xs > ys) ? xs : ys) : ((xs < ys) ? xs : ys);
            xb = takeMax ? ((xb > yb) ? xb : yb) : ((xb < yb) ? xb : yb);
        }
    }
    sure[tid] = xs; bnd[tid] = xb;
    __syncthreads();
    if (B > 1024) {    // statistically never; full 2048 network re-sorts bnd
        for (int k = 2; k <= 2048; k <<= 1)
            for (int j = k >> 1; j > 0; j >>= 1) {
                int i = ((tid & ~(j - 1)) << 1) | (tid & (j - 1));
                int pp = i | j;
                u64 A = bnd[i], Bv = bnd[pp];
                bool up = ((i & k) == 0);
                if (up ? (A < Bv) : (A > Bv)) { bnd[i] = Bv; bnd[pp] = A; }
                __syncthreads();
            }
    }
    int r = tid;
    u64 c = 0ULL;
    if (r < K_TOP) c = (r < (int)S) ? sure[r] : ((r - (int)S < (int)B) ? bnd[r - (int)S] : 0ULL);

    float sm = NEGF, x0 = 0.f, y0 = 0.f, x1 = 0.f, y1 = 0.f;
    float b0 = 0.f, b1 = 0.f, b2 = 0.f, b3 = 0.f;
    bool valid = false;
    if (r < K_TOP && c != 0ULL) {
        int idx = (int)(~(unsigned)c);
        int m = MS5[lvl];
        if ((unsigned)idx >= (unsigned)m) idx = 0;   // safety (never expected)
        const float* lg = p.lg[lvl];
        const float* dl = p.dl[lvl];
        float score = lg[(size_t)img * m + idx];
        int a   = idx % 3;
        int loc = idx / 3;
        int gw  = GW[lvl];
        int x = loc % gw, y = loc / gw;
        double ssz = (double)SIZEI[lvl];
        double arr = (a == 0) ? 0.5 : ((a == 1) ? 1.0 : 2.0);
        double wd = sqrt(ssz * ssz / arr);
        double hd = arr * wd;
        float sx = (float)x * STRIDEF[lvl];
        float sy = (float)y * STRIDEF[lvl];
        float a0 = sx + (float)(-wd * 0.5);
        float a1 = sy + (float)(-hd * 0.5);
        float a2 = sx + (float)( wd * 0.5);
        float a3 = sy + (float)( hd * 0.5);
        float aw = a2 - a0, ah = a3 - a1;
        float acx = a0 + 0.5f * aw, acy = a1 + 0.5f * ah;
        size_t db = ((size_t)img * m + idx) * 4;
        float dx = dl[db], dy = dl[db + 1], dwv = dl[db + 2], dhv = dl[db + 3];
        const float CL = 4.135166556742356f;   // log(1000/16)
        float pw = expf(fminf(dwv, CL)) * aw;
        float ph = expf(fminf(dhv, CL)) * ah;
        float pcx = dx * aw + acx;
        float pcy = dy * ah + acy;
        x0 = pcx - 0.5f * pw; y0 = pcy - 0.5f * ph;
        x1 = pcx + 0.5f * pw; y1 = pcy + 0.5f * ph;
        x0 = fminf(fmaxf(x0, 0.f), 2048.f);
        x1 = fminf(fmaxf(x1, 0.f), 2048.f);
        y0 = fminf(fmaxf(y0, 0.f), 1344.f);
        y1 = fminf(fmaxf(y1, 0.f), 1344.f);
        bool keep = ((x1 - x0) > 0.f) && ((y1 - y0) > 0.f);
        valid = keep;
        sm = score;
        float off = (float)lvl * 2049.0f;
        b0 = x0 + off; b1 = y0 + off; b2 = x1 + off; b3 = y1 + off;
    }
    // ballot-based valid compaction (exclusive pos, total)
    u64 vm = __ballot(valid);
    int lanePre = (int)__popcll(vm & ((1ULL << lane) - 1ULL));
    if (lane == 0) wTot[wv] = (int)__popcll(vm);
    __syncthreads();
    int offset = 0, total = 0;
    for (int w2 = 0; w2 < 16; ++w2) {
        int t2 = wTot[w2];
        total += t2;
        if (w2 < wv) offset += t2;
    }
    int pos = offset + lanePre;
    if (valid) {
        int ci = img * NCAND + lvl * K_TOP + pos;
        cscore[ci] = sm;
        cbox[ci]   = make_float4(x0, y0, x1, y1);
        cobox[ci]  = make_float4(b0, b1, b2, b3);
        cog[ci]    = (unsigned)r;
    }
    if (tid == 0) vcnt[task] = (unsigned)total;
}

// ---------------- pass 3: rank-merge, 1 block per (img,lvl), scatter to global ----
__global__ __launch_bounds__(1024) void kMergeRank(
        const float* __restrict__ cscore,
        const float4* __restrict__ cobox,
        const unsigned* __restrict__ cog,
        const unsigned* __restrict__ vcnt,
        float4* __restrict__ mobG,
        unsigned* __restrict__ midxG) {
    int task = blockIdx.x;
    int img = task / NLVL, lvl = task % NLVL;
    int tid = threadIdx.x;
    const int imgb = img * NCAND;
    __shared__ u64 compO[4 * K_TOP];    // other 4 levels' composites (32 KB)
    __shared__ int LSs[NLVL];
    if (tid < NLVL) LSs[tid] = (int)vcnt[img * NLVL + tid];
    __syncthreads();
    for (int idx = tid; idx < 4 * K_TOP; idx += 1024) {
        int q = idx / K_TOP, gl2 = idx - q * K_TOP;
        int l2 = q + (q >= lvl ? 1 : 0);
        u64 c = 0ULL;
        if (gl2 < LSs[l2]) {
            int g2 = l2 * K_TOP + gl2;
            unsigned og = (unsigned)(l2 * K_TOP) + cog[imgb + g2];
            c = ((u64)key_of(cscore[imgb + g2]) << 32) | (unsigned)(~og);
        }
        compO[idx] = c;
    }
    __syncthreads();
    int gl = tid;
    if (gl < LSs[lvl]) {
        int g = lvl * K_TOP + gl;
        float4 pref = cobox[imgb + g];             // overlap HBM with LDS searches
        unsigned og = (unsigned)(lvl * K_TOP) + cog[imgb + g];
        u64 c = ((u64)key_of(cscore[imgb + g]) << 32) | (unsigned)(~og);
        int l0 = 0, h0 = LSs[0 + (0 >= lvl ? 1 : 0)];
        int l1 = 0, h1 = LSs[1 + (1 >= lvl ? 1 : 0)];
        int l2 = 0, h2 = LSs[2 + (2 >= lvl ? 1 : 0)];
        int l3 = 0, h3 = LSs[3 + (3 >= lvl ? 1 : 0)];
#pragma unroll
        for (int step = 0; step < 10; ++step) {    // lists <= 1000 -> 10 steps
            if (l0 < h0) { int m0 = (l0 + h0) >> 1; if (compO[0 * K_TOP + m0] > c) l0 = m0 + 1; else h0 = m0; }
            if (l1 < h1) { int m1 = (l1 + h1) >> 1; if (compO[1 * K_TOP + m1] > c) l1 = m1 + 1; else h1 = m1; }
            if (l2 < h2) { int m2 = (l2 + h2) >> 1; if (compO[2 * K_TOP + m2] > c) l2 = m2 + 1; else h2 = m2; }
            if (l3 < h3) { int m3 = (l3 + h3) >> 1; if (compO[3 * K_TOP + m3] > c) l3 = m3 + 1; else h3 = m3; }
        }
        int pos = gl + l0 + l1 + l2 + l3;
        mobG[(size_t)img * NPAD + pos] = pref;
        midxG[imgb + pos] = (unsigned)g;
    }
}

// ---------------- pass 4: greedy scan; within-word selection via MIS fixpoint ----------------
__global__ __launch_bounds__(1024) void kScan(
        const float4* __restrict__ mobG,
        const unsigned* __restrict__ midxG,
        const float* __restrict__ cscore,
        const float4* __restrict__ cbox,
        const unsigned* __restrict__ vcnt,
        float* __restrict__ out) {
    int img = blockIdx.x;
    int tid = threadIdx.x;
    int lane = tid & 63;
    int wave = tid >> 6;
    __shared__ float4 wboxS[2][64];     // double buffer (prefetch during serial)
    __shared__ u64    diagWS[64];
    __shared__ u64    partS[16];
    __shared__ float4 pboxAll[NPOST];
    __shared__ unsigned emS[NPOST];
    __shared__ int stateS[2];           // {emitted, done}
    const int imgb = img * NCAND;

    int V = 0;
    for (int l = 0; l < NLVL; ++l) V += (int)vcnt[img * NLVL + l];

    if (tid < 64 && V > 0) wboxS[0][tid] = mobG[(size_t)img * NPAD + tid];
    __syncthreads();

    int emitted = 0;
    bool done = (V == 0);
    for (int w = 0; w < NWORDS && !done; ++w) {
        int base = w * 64;
        if (base >= V) break;
        int buf = w & 1;
        float4 bc = wboxS[buf][lane];
        float  arc = (bc.z - bc.x) * (bc.w - bc.y);
        bool supp = false;
        for (int t = wave; t < emitted; t += 16) {
            float4 bp = pboxAll[t];
            float arp = (bp.z - bp.x) * (bp.w - bp.y);
            float ltx = fmaxf(bc.x, bp.x), lty = fmaxf(bc.y, bp.y);
            float rbx = fminf(bc.z, bp.z), rby = fminf(bc.w, bp.w);
            float wx = fmaxf(rbx - ltx, 0.f), wy = fmaxf(rby - lty, 0.f);
            float inter = wx * wy;
            float denom = (arc + arp) - inter + 1e-9f;
            supp |= (inter / denom) > 0.7f;
        }
        u64 sb = __ballot(supp);
        if (lane == 0) partS[wave] = sb;
#pragma unroll
        for (int rr = 0; rr < 4; ++rr) {
            int r = wave * 4 + rr;
            float4 bp = wboxS[buf][r];
            float arp = (bp.z - bp.x) * (bp.w - bp.y);
            float ltx = fmaxf(bc.x, bp.x), lty = fmaxf(bc.y, bp.y);
            float rbx = fminf(bc.z, bp.z), rby = fminf(bc.w, bp.w);
            float wx = fmaxf(rbx - ltx, 0.f), wy = fmaxf(rby - lty, 0.f);
            float inter = wx * wy;
            float denom = (arc + arp) - inter + 1e-9f;
            bool pred = (inter / denom) > 0.7f;
            u64 db = __ballot(pred);
            if (lane == 0) diagWS[r] = db;
        }
        __syncthreads();
        if (wave == 0) {
            u64 dreg = diagWS[lane];           // lane's own adjacency row (symmetric)
            u64 smv = partS[0];
#pragma unroll
            for (int q = 1; q < 16; ++q) smv |= partS[q];
            int rem = V - base;
            u64 vmask = (rem >= 64) ? ~0ULL : ((1ULL << rem) - 1ULL);
            u64 A = (~smv) & vmask;
            u64 below = (1ULL << lane) - 1ULL;
            bool inA = (A >> lane) & 1ULL;
            u64 S = A;
            while (true) {
                bool pred = inA && ((dreg & S & below) == 0ULL);
                u64 Snew = __ballot(pred);
                if (Snew == S) break;
                S = Snew;
            }
            int cnt = __popcll(S);
            int rem0 = NPOST - emitted;
            int rank = __popcll(S & below);
            bool kept = ((S >> lane) & 1ULL) && (rank < rem0);
            if (kept) {
                emS[emitted + rank]     = (unsigned)(base + lane);
                pboxAll[emitted + rank] = wboxS[buf][lane];
            }
            if (lane == 0) {
                int emadd = (cnt < rem0) ? cnt : rem0;
                stateS[0] = emitted + emadd;
                stateS[1] = (cnt >= rem0) ? 1 : 0;
            }
        } else if (wave == 15) {
            int nb = base + 64;
            if (nb < V && (w + 1) < NWORDS)
                wboxS[buf ^ 1][lane] = mobG[(size_t)img * NPAD + nb + lane];
        }
        __syncthreads();
        emitted = stateS[0];
        done = (stateS[1] != 0);
    }
    __syncthreads();
    for (int rr = tid; rr < NPOST; rr += 1024) {
        float* o = out + ((size_t)img * NPOST + rr) * 5;
        if (rr < emitted) {
            unsigned i = emS[rr];
            unsigned g = midxG[imgb + i];
            float4 cb = cbox[imgb + g];
            float sc = cscore[imgb + g];
            o[0] = cb.x; o[1] = cb.y; o[2] = cb.z; o[3] = cb.w; o[4] = sc;
        } else {
            o[0] = 0.f; o[1] = 0.f; o[2] = 0.f; o[3] = 0.f; o[4] = NEGF;
        }
    }
}

extern "C" void kernel_launch(void* const* d_in, const int* in_sizes, int n_in,
                              void* d_out, int out_size, void* d_ws, size_t ws_size,
                              hipStream_t stream) {
    Ptrs P;
    for (int l = 0; l < 5; ++l) {
        P.lg[l] = (const float*)d_in[2 * l];
        P.dl[l] = (const float*)d_in[2 * l + 1];
    }
    char* w = (char*)d_ws;
    size_t off = 0;
    auto alloc = [&](size_t bytes) -> void* {
        void* pp = (void*)(w + off);
        off = (off + bytes + 255) & ~(size_t)255;
        return pp;
    };
    unsigned* bcnt   = (unsigned*)alloc((size_t)NIMG * NSLOT * 4);
    u64* compS       = (u64*)alloc((size_t)NIMG * NSLOT * SCAP * 8);      // 3.01 MB
    unsigned* histFB = (unsigned*)alloc((size_t)NTASK * NB1 * 4);         // 2.6 MB, fallback only
    float*  cscore   = (float*)alloc((size_t)NTASK * K_TOP * 4);
    float4* cbox     = (float4*)alloc((size_t)NTASK * K_TOP * 16);
    float4* cobox    = (float4*)alloc((size_t)NTASK * K_TOP * 16);
    unsigned* cog    = (unsigned*)alloc((size_t)NTASK * K_TOP * 4);
    unsigned* vcnt   = (unsigned*)alloc(NTASK * 4);
    float4* mobG     = (float4*)alloc((size_t)NIMG * NPAD * 16);
    unsigned* midxG  = (unsigned*)alloc((size_t)NIMG * NCAND * 4);
    (void)in_sizes; (void)n_in; (void)out_size; (void)ws_size;

    kStage<<<dim3(NSLOT, NIMG), 1024, 0, stream>>>(P, compS, bcnt);
    kSortSelect<<<NTASK, 1024, 0, stream>>>(P, compS, bcnt, histFB,
                                            cscore, cbox, cobox, cog, vcnt);
    kMergeRank<<<NTASK, 1024, 0, stream>>>(cscore, cobox, cog, vcnt, mobG, midxG);
    kScan<<<NIMG, 1024, 0, stream>>>(mobG, midxG, cscore, cbox, vcnt,
                                     (float*)d_out);
}

// Round 30
// 62.018 us; speedup vs baseline: 1.2553x; 1.2553x over previous
//
#include <hip/hip_runtime.h>
#include <cstdint>
#include <cstddef>

#define NB1      16384      // 2^14 bins (fallback path only)
#define L1SHIFT  18
#define K_TOP    1000
#define NCAND    5000
#define NIMG     8
#define NLVL     5
#define NTASK    40
#define NPOST    300
#define NEGF     (-1e9f)
#define NWORDS   79         // ceil(5000/64)
#define NPAD     (NWORDS * 64)
#define NSLOT    23         // per-image slices: 16+4+1+1+1
#define SCAP     2048       // per-slice staged-candidate cap

typedef unsigned long long u64;

struct Ptrs {
    const float* lg[5];
    const float* dl[5];
};

__device__ __forceinline__ unsigned key_of(float f) {
    unsigned u = __float_as_uint(f);
    return (u & 0x80000000u) ? ~u : (u | 0x80000000u);
}

__device__ __forceinline__ void lvl_of_slot(int bx, int& lvl, int& lb, int& gx, int& m) {
    lvl = (bx < 16) ? 0 : (bx < 20) ? 1 : (bx < 21) ? 2 : (bx < 22) ? 3 : 4;
    const int S0[5] = {0, 16, 20, 21, 22};
    const int GX[5] = {16, 4, 1, 1, 1};
    const int MS[5] = {516096, 129024, 32256, 8064, 2016};
    lb = bx - S0[lvl];
    gx = GX[lvl];
    m  = MS[lvl];
}

// ---------------- pass 1: pure stream + fixed-threshold staging (no histogram) ----
// Tf = {2.75,2.3,1.7,0.9,-0.35}: staged/task ~{1538,1384,1437,1484,1284}, all
// >=10 sigma above K=1000 (cutoffs z={2.89,2.42,1.87,1.155,0.01}); kSortSelect
// verifies exactly by counts and falls back to a histogram select on mismatch.
__global__ __launch_bounds__(1024) void kStage(Ptrs p,
                                               u64* __restrict__ compS,
                                               unsigned* __restrict__ bcnt) {
    int lvl, lb, gx, m;
    lvl_of_slot(blockIdx.x, lvl, lb, gx, m);
    int img = blockIdx.y;
    size_t slice = (size_t)img * NSLOT + blockIdx.x;
    const float* lg = p.lg[lvl];
    const float TF5[5] = {2.75f, 2.3f, 1.7f, 0.9f, -0.35f};
    float Tf = TF5[lvl];
    __shared__ unsigned lcnt;
    int tid = threadIdx.x, lane = tid & 63;
    if (tid == 0) lcnt = 0u;
    __syncthreads();
    int m4 = m >> 2;
    int chunk4 = (m4 + gx - 1) / gx;
    int start4 = lb * chunk4;
    int end4   = min(start4 + chunk4, m4);
    const float4* src = (const float4*)(lg + (size_t)img * m);
    u64 below = (1ULL << lane) - 1ULL;
    for (int ib = start4; ib < end4; ib += 1024) {
        int i = ib + tid;
        bool inb = (i < end4);
        float4 v = inb ? src[i] : make_float4(0.f, 0.f, 0.f, 0.f);
        int j = i * 4;
        bool p0 = inb && (v.x > Tf);
        bool p1 = inb && (v.y > Tf);
        bool p2 = inb && (v.z > Tf);
        bool p3 = inb && (v.w > Tf);
        u64 m0 = __ballot(p0);
        u64 m1 = __ballot(p1);
        u64 m2 = __ballot(p2);
        u64 m3 = __ballot(p3);
        unsigned n0 = (unsigned)__popcll(m0), n1 = (unsigned)__popcll(m1);
        unsigned n2 = (unsigned)__popcll(m2), n3 = (unsigned)__popcll(m3);
        unsigned ntot = n0 + n1 + n2 + n3;
        unsigned base = 0;
        if (lane == 0 && ntot) base = atomicAdd(&lcnt, ntot);
        base = (unsigned)__shfl((int)base, 0, 64);
        if (p0) { unsigned q = base + (unsigned)__popcll(m0 & below);
                  if (q < SCAP) compS[slice * SCAP + q] = ((u64)key_of(v.x) << 32) | (unsigned)(~(unsigned)(j)); }
        if (p1) { unsigned q = base + n0 + (unsigned)__popcll(m1 & below);
                  if (q < SCAP) compS[slice * SCAP + q] = ((u64)key_of(v.y) << 32) | (unsigned)(~(unsigned)(j + 1)); }
        if (p2) { unsigned q = base + n0 + n1 + (unsigned)__popcll(m2 & below);
                  if (q < SCAP) compS[slice * SCAP + q] = ((u64)key_of(v.z) << 32) | (unsigned)(~(unsigned)(j + 2)); }
        if (p3) { unsigned q = base + n0 + n1 + n2 + (unsigned)__popcll(m3 & below);
                  if (q < SCAP) compS[slice * SCAP + q] = ((u64)key_of(v.w) << 32) | (unsigned)(~(unsigned)(j + 3)); }
    }
    __syncthreads();
    if (tid == 0) bcnt[slice] = lcnt;            // RAW count (cap checked later)
}

// ---------------- pass 2: count-verified gather + register bitonic, decode ------
// Thi = {2.97,2.5,1.95,1.25,0.15}: cS ~{768,801,825,852,888} <= 1024 (6-9 sigma)
// and cB ~{770,583,612,632,396} <= 1024 (>=6 sigma) -> 2048-network never runs.
__global__ __launch_bounds__(1024) void kSortSelect(
        Ptrs p,
        const u64* __restrict__ compS,
        const unsigned* __restrict__ bcnt,
        unsigned* __restrict__ histFB,
        float* __restrict__ cscore,
        float4* __restrict__ cbox,
        float4* __restrict__ cobox,
        unsigned* __restrict__ cog,
        unsigned* __restrict__ vcnt) {
    int task = blockIdx.x;
    int img = task / NLVL, lvl = task % NLVL;
    int tid = threadIdx.x, lane = tid & 63, wv = tid >> 6;
    const int   MS5[5]    = {516096, 129024, 32256, 8064, 2016};
    const int   GW[5]     = {512, 256, 128, 64, 32};
    const float STRIDEF[5]= {4.f, 8.f, 16.f, 32.f, 64.f};
    const int   SIZEI[5]  = {32, 64, 128, 256, 512};
    const float THI5[5]   = {2.97f, 2.5f, 1.95f, 1.25f, 0.15f};   // sure/bnd split
    __shared__ u64 sure[1024];
    __shared__ u64 bnd[2048];
    __shared__ unsigned sblkF[256];
    __shared__ int tmpF[8];
    __shared__ unsigned cS, cB;
    __shared__ unsigned soff[17];
    __shared__ int wTot[16];
    __shared__ int fbS;
    unsigned KH = key_of(THI5[lvl]);
    if (tid == 0) { cS = 0u; cB = 0u; }
    sure[tid] = 0ULL;
    bnd[tid] = 0ULL; bnd[tid + 1024] = 0ULL;
    if (tid < 17) soff[tid] = 0u;
    if (tid == 0) fbS = 0;
    __syncthreads();
    const int S0[5] = {0, 16, 20, 21, 22};
    const int NS[5] = {16, 4, 1, 1, 1};
    int s0 = S0[lvl], ns = NS[lvl];
    if (tid < ns) {
        unsigned raw = bcnt[(size_t)img * NSLOT + s0 + tid];
        if (raw > SCAP) atomicOr((unsigned*)&fbS, 1u);   // slice capped -> fallback
        soff[tid + 1] = min(raw, (unsigned)SCAP);
    }
    __syncthreads();
    if (tid == 0)
        for (int s = 1; s <= 16; ++s) soff[s] += soff[s - 1];
    __syncthreads();
    int tot = (int)soff[ns];
    u64 below = (1ULL << lane) - 1ULL;
    for (int ib = 0; ib < tot; ib += 1024) {
        int idx = ib + tid;
        bool inb = (idx < tot);
        u64 c = 0ULL;
        if (inb) {
            int s = 0;
            while ((int)soff[s + 1] <= idx) ++s;     // <=16 LDS reads
            c = compS[((size_t)img * NSLOT + s0 + s) * SCAP + (idx - (int)soff[s])];
        }
        bool pS = inb && ((unsigned)(c >> 32) > KH);   // v > Tf_hi
        bool pB = inb && !pS;                          // Tf < v <= Tf_hi
        u64 mS = __ballot(pS);
        u64 mB = __ballot(pB);
        unsigned bS = 0, bB = 0;
        if (lane == 0) {
            if (mS) bS = atomicAdd(&cS, (unsigned)__popcll(mS));
            if (mB) bB = atomicAdd(&cB, (unsigned)__popcll(mB));
        }
        bS = (unsigned)__shfl((int)bS, 0, 64);
        bB = (unsigned)__shfl((int)bB, 0, 64);
        if (pS) { unsigned q = bS + (unsigned)__popcll(mS & below); if (q < 1024u) sure[q] = c; }
        if (pB) { unsigned q = bB + (unsigned)__popcll(mB & below); if (q < 2048u) bnd[q] = c; }
    }
    __syncthreads();
    // ---- exact verification (pure counts) ----
    if (tid == 0) {
        if (cS > 1024u || cB > 2048u || (cS + cB) < (unsigned)K_TOP) fbS = 1;
    }
    __syncthreads();
    // ---- fallback: histogram select over raw logits, hist in GLOBAL scratch ----
    if (fbS) {
        int mm = MS5[lvl];
        int mm4 = mm >> 2;
        const float4* s4 = (const float4*)(p.lg[lvl] + (size_t)img * mm);
        unsigned* h = histFB + (size_t)task * NB1;
        for (int i = tid; i < NB1; i += 1024) h[i] = 0u;
        __syncthreads();
        for (int i = tid; i < mm4; i += 1024) {
            float4 v = s4[i];
            atomicAdd(&h[key_of(v.x) >> L1SHIFT], 1u);
            atomicAdd(&h[key_of(v.y) >> L1SHIFT], 1u);
            atomicAdd(&h[key_of(v.z) >> L1SHIFT], 1u);
            atomicAdd(&h[key_of(v.w) >> L1SHIFT], 1u);
        }
        __syncthreads();
        if (tid < 256) {
            unsigned coarse = 0;
            for (int ii = 0; ii < 64; ++ii) coarse += h[tid * 64 + ii];
            sblkF[tid] = coarse;
        }
        __syncthreads();
        unsigned SSv = 0;
        if (tid < 256) {
            SSv = sblkF[tid];
            for (int d = 1; d < 64; d <<= 1) {
                unsigned o = __shfl_down(SSv, d, 64);
                if (lane < 64 - d) SSv += o;
            }
            unsigned wtot = __shfl(SSv, 0, 64);
            if (lane == 0) tmpF[4 + wv] = (int)wtot;
        }
        __syncthreads();
        if (tid < 256) {
            unsigned add = 0;
            for (int w2 = wv + 1; w2 < 4; ++w2) add += (unsigned)tmpF[4 + w2];
            SSv += add;
            bool pred = (SSv >= (unsigned)K_TOP);
            u64 mk = __ballot(pred);
            if (lane == 0)
                tmpF[wv] = mk ? (wv * 64 + (63 - __builtin_clzll(mk))) : -1;
        }
        __syncthreads();
        int tb = max(max(tmpF[0], tmpF[1]), max(tmpF[2], tmpF[3]));
        __syncthreads();
        if (tid == 0) {
            unsigned above = 0;
            for (int b2 = tb + 1; b2 < 256; ++b2) above += sblkF[b2];
            unsigned rem = (unsigned)K_TOP - above;
            unsigned suf = 0;
            int pfx = tb * 64;
            for (int u2 = 63; u2 >= 0; --u2) {
                suf += h[tb * 64 + u2];
                if (suf >= rem) { pfx = tb * 64 + u2; break; }
            }
            tmpF[0] = pfx;
        }
        __syncthreads();
        unsigned pfx = (unsigned)tmpF[0];
        if (tid == 0) { cS = 0u; cB = 0u; }
        sure[tid] = 0ULL;
        bnd[tid] = 0ULL; bnd[tid + 1024] = 0ULL;
        __syncthreads();
        for (int ib = 0; ib < mm4; ib += 1024) {
            int i = ib + tid;
            bool inb = (i < mm4);
            float4 v = inb ? s4[i] : make_float4(0.f, 0.f, 0.f, 0.f);
            int j = i * 4;
            unsigned kk[4] = { key_of(v.x), key_of(v.y), key_of(v.z), key_of(v.w) };
#pragma unroll
            for (int e = 0; e < 4; ++e) {
                unsigned bin = kk[e] >> L1SHIFT;
                bool pS2 = inb && (bin > pfx);
                bool pB2 = inb && (bin == pfx);
                u64 mS2 = __ballot(pS2);
                u64 mB2 = __ballot(pB2);
                unsigned bS2 = 0, bB2 = 0;
                if (lane == 0) {
                    if (mS2) bS2 = atomicAdd(&cS, (unsigned)__popcll(mS2));
                    if (mB2) bB2 = atomicAdd(&cB, (unsigned)__popcll(mB2));
                }
                bS2 = (unsigned)__shfl((int)bS2, 0, 64);
                bB2 = (unsigned)__shfl((int)bB2, 0, 64);
                u64 cc = ((u64)kk[e] << 32) | (unsigned)(~(unsigned)(j + e));
                if (pS2) { unsigned q = bS2 + (unsigned)__popcll(mS2 & below); if (q < 1024u) sure[q] = cc; }
                if (pB2) { unsigned q = bB2 + (unsigned)__popcll(mB2 & below); if (q < 2048u) bnd[q] = cc; }
            }
        }
        __syncthreads();
    }
    unsigned S = cS;
    unsigned B = cB;
    // register bitonic (desc), 1 elem/thread per array; shfl for j<64, LDS for j>=64
    u64 xs = sure[tid], xb = bnd[tid];
    for (int k = 2; k <= 1024; k <<= 1) {
        for (int j = k >> 1; j > 0; j >>= 1) {
            bool up   = ((tid & k) == 0);
            bool iLow = ((tid & j) == 0);
            u64 ys, yb;
            if (j >= 64) {
                sure[tid] = xs; bnd[tid] = xb;
                __syncthreads();
                ys = sure[tid ^ j]; yb = bnd[tid ^ j];
                __syncthreads();
            } else {
                ys = __shfl_xor(xs, j, 64);
                yb = __shfl_xor(xb, j, 64);
            }
            bool takeMax = (iLow == up);
            xs = takeMax ? ((xs > ys) ? xs : ys) : ((xs < ys) ? xs : ys);
            xb = takeMax ? ((xb > yb) ? xb : yb) : ((xb < yb) ? xb : yb);
        }
    }
    sure[tid] = xs; bnd[tid] = xb;
    __syncthreads();
    if (B > 1024) {    // correctness fallback only; thresholds keep B <= 1024
        for (int k = 2; k <= 2048; k <<= 1)
            for (int j = k >> 1; j > 0; j >>= 1) {
                int i = ((tid & ~(j - 1)) << 1) | (tid & (j - 1));
                int pp = i | j;
                u64 A = bnd[i], Bv = bnd[pp];
                bool up = ((i & k) == 0);
                if (up ? (A < Bv) : (A > Bv)) { bnd[i] = Bv; bnd[pp] = A; }
                __syncthreads();
            }
    }
    int r = tid;
    u64 c = 0ULL;
    if (r < K_TOP) c = (r < (int)S) ? sure[r] : ((r - (int)S < (int)B) ? bnd[r - (int)S] : 0ULL);

    float sm = NEGF, x0 = 0.f, y0 = 0.f, x1 = 0.f, y1 = 0.f;
    float b0 = 0.f, b1 = 0.f, b2 = 0.f, b3 = 0.f;
    bool valid = false;
    if (r < K_TOP && c != 0ULL) {
        int idx = (int)(~(unsigned)c);
        int m = MS5[lvl];
        if ((unsigned)idx >= (unsigned)m) idx = 0;   // safety (never expected)
        const float* lg = p.lg[lvl];
        const float* dl = p.dl[lvl];
        float score = lg[(size_t)img * m + idx];
        int a   = idx % 3;
        int loc = idx / 3;
        int gw  = GW[lvl];
        int x = loc % gw, y = loc / gw;
        double ssz = (double)SIZEI[lvl];
        double arr = (a == 0) ? 0.5 : ((a == 1) ? 1.0 : 2.0);
        double wd = sqrt(ssz * ssz / arr);
        double hd = arr * wd;
        float sx = (float)x * STRIDEF[lvl];
        float sy = (float)y * STRIDEF[lvl];
        float a0 = sx + (float)(-wd * 0.5);
        float a1 = sy + (float)(-hd * 0.5);
        float a2 = sx + (float)( wd * 0.5);
        float a3 = sy + (float)( hd * 0.5);
        float aw = a2 - a0, ah = a3 - a1;
        float acx = a0 + 0.5f * aw, acy = a1 + 0.5f * ah;
        size_t db = ((size_t)img * m + idx) * 4;
        float dx = dl[db], dy = dl[db + 1], dwv = dl[db + 2], dhv = dl[db + 3];
        const float CL = 4.135166556742356f;   // log(1000/16)
        float pw = expf(fminf(dwv, CL)) * aw;
        float ph = expf(fminf(dhv, CL)) * ah;
        float pcx = dx * aw + acx;
        float pcy = dy * ah + acy;
        x0 = pcx - 0.5f * pw; y0 = pcy - 0.5f * ph;
        x1 = pcx + 0.5f * pw; y1 = pcy + 0.5f * ph;
        x0 = fminf(fmaxf(x0, 0.f), 2048.f);
        x1 = fminf(fmaxf(x1, 0.f), 2048.f);
        y0 = fminf(fmaxf(y0, 0.f), 1344.f);
        y1 = fminf(fmaxf(y1, 0.f), 1344.f);
        bool keep = ((x1 - x0) > 0.f) && ((y1 - y0) > 0.f);
        valid = keep;
        sm = score;
        float off = (float)lvl * 2049.0f;
        b0 = x0 + off; b1 = y0 + off; b2 = x1 + off; b3 = y1 + off;
    }
    // ballot-based valid compaction (exclusive pos, total)
    u64 vm = __ballot(valid);
    int lanePre = (int)__popcll(vm & ((1ULL << lane) - 1ULL));
    if (lane == 0) wTot[wv] = (int)__popcll(vm);
    __syncthreads();
    int offset = 0, total = 0;
    for (int w2 = 0; w2 < 16; ++w2) {
        int t2 = wTot[w2];
        total += t2;
        if (w2 < wv) offset += t2;
    }
    int pos = offset + lanePre;
    if (valid) {
        int ci = img * NCAND + lvl * K_TOP + pos;
        cscore[ci] = sm;
        cbox[ci]   = make_float4(x0, y0, x1, y1);
        cobox[ci]  = make_float4(b0, b1, b2, b3);
        cog[ci]    = (unsigned)r;
    }
    if (tid == 0) vcnt[task] = (unsigned)total;
}

// ---------------- pass 3: rank-merge, 1 block per (img,lvl), scatter to global ----
__global__ __launch_bounds__(1024) void kMergeRank(
        const float* __restrict__ cscore,
        const float4* __restrict__ cobox,
        const unsigned* __restrict__ cog,
        const unsigned* __restrict__ vcnt,
        float4* __restrict__ mobG,
        unsigned* __restrict__ midxG) {
    int task = blockIdx.x;
    int img = task / NLVL, lvl = task % NLVL;
    int tid = threadIdx.x;
    const int imgb = img * NCAND;
    __shared__ u64 compO[4 * K_TOP];    // other 4 levels' composites (32 KB)
    __shared__ int LSs[NLVL];
    if (tid < NLVL) LSs[tid] = (int)vcnt[img * NLVL + tid];
    __syncthreads();
    for (int idx = tid; idx < 4 * K_TOP; idx += 1024) {
        int q = idx / K_TOP, gl2 = idx - q * K_TOP;
        int l2 = q + (q >= lvl ? 1 : 0);
        u64 c = 0ULL;
        if (gl2 < LSs[l2]) {
            int g2 = l2 * K_TOP + gl2;
            unsigned og = (unsigned)(l2 * K_TOP) + cog[imgb + g2];
            c = ((u64)key_of(cscore[imgb + g2]) << 32) | (unsigned)(~og);
        }
        compO[idx] = c;
    }
    __syncthreads();
    int gl = tid;
    if (gl < LSs[lvl]) {
        int g = lvl * K_TOP + gl;
        float4 pref = cobox[imgb + g];             // overlap HBM with LDS searches
        unsigned og = (unsigned)(lvl * K_TOP) + cog[imgb + g];
        u64 c = ((u64)key_of(cscore[imgb + g]) << 32) | (unsigned)(~og);
        int l0 = 0, h0 = LSs[0 + (0 >= lvl ? 1 : 0)];
        int l1 = 0, h1 = LSs[1 + (1 >= lvl ? 1 : 0)];
        int l2 = 0, h2 = LSs[2 + (2 >= lvl ? 1 : 0)];
        int l3 = 0, h3 = LSs[3 + (3 >= lvl ? 1 : 0)];
#pragma unroll
        for (int step = 0; step < 10; ++step) {    // lists <= 1000 -> 10 steps
            if (l0 < h0) { int m0 = (l0 + h0) >> 1; if (compO[0 * K_TOP + m0] > c) l0 = m0 + 1; else h0 = m0; }
            if (l1 < h1) { int m1 = (l1 + h1) >> 1; if (compO[1 * K_TOP + m1] > c) l1 = m1 + 1; else h1 = m1; }
            if (l2 < h2) { int m2 = (l2 + h2) >> 1; if (compO[2 * K_TOP + m2] > c) l2 = m2 + 1; else h2 = m2; }
            if (l3 < h3) { int m3 = (l3 + h3) >> 1; if (compO[3 * K_TOP + m3] > c) l3 = m3 + 1; else h3 = m3; }
        }
        int pos = gl + l0 + l1 + l2 + l3;
        mobG[(size_t)img * NPAD + pos] = pref;
        midxG[imgb + pos] = (unsigned)g;
    }
}

// ---------------- pass 4: greedy scan; within-word selection via MIS fixpoint ----------------
__global__ __launch_bounds__(1024) void kScan(
        const float4* __restrict__ mobG,
        const unsigned* __restrict__ midxG,
        const float* __restrict__ cscore,
        const float4* __restrict__ cbox,
        const unsigned* __restrict__ vcnt,
        float* __restrict__ out) {
    int img = blockIdx.x;
    int tid = threadIdx.x;
    int lane = tid & 63;
    int wave = tid >> 6;
    __shared__ float4 wboxS[2][64];     // double buffer (prefetch during serial)
    __shared__ u64    diagWS[64];
    __shared__ u64    partS[16];
    __shared__ float4 pboxAll[NPOST];
    __shared__ unsigned emS[NPOST];
    __shared__ int stateS[2];           // {emitted, done}
    const int imgb = img * NCAND;

    int V = 0;
    for (int l = 0; l < NLVL; ++l) V += (int)vcnt[img * NLVL + l];

    if (tid < 64 && V > 0) wboxS[0][tid] = mobG[(size_t)img * NPAD + tid];
    __syncthreads();

    int emitted = 0;
    bool done = (V == 0);
    for (int w = 0; w < NWORDS && !done; ++w) {
        int base = w * 64;
        if (base >= V) break;
        int buf = w & 1;
        float4 bc = wboxS[buf][lane];
        float  arc = (bc.z - bc.x) * (bc.w - bc.y);
        bool supp = false;
        for (int t = wave; t < emitted; t += 16) {
            float4 bp = pboxAll[t];
            float arp = (bp.z - bp.x) * (bp.w - bp.y);
            float ltx = fmaxf(bc.x, bp.x), lty = fmaxf(bc.y, bp.y);
            float rbx = fminf(bc.z, bp.z), rby = fminf(bc.w, bp.w);
            float wx = fmaxf(rbx - ltx, 0.f), wy = fmaxf(rby - lty, 0.f);
            float inter = wx * wy;
            float denom = (arc + arp) - inter + 1e-9f;
            supp |= (inter / denom) > 0.7f;
        }
        u64 sb = __ballot(supp);
        if (lane == 0) partS[wave] = sb;
#pragma unroll
        for (int rr = 0; rr < 4; ++rr) {
            int r = wave * 4 + rr;
            float4 bp = wboxS[buf][r];
            float arp = (bp.z - bp.x) * (bp.w - bp.y);
            float ltx = fmaxf(bc.x, bp.x), lty = fmaxf(bc.y, bp.y);
            float rbx = fminf(bc.z, bp.z), rby = fminf(bc.w, bp.w);
            float wx = fmaxf(rbx - ltx, 0.f), wy = fmaxf(rby - lty, 0.f);
            float inter = wx * wy;
            float denom = (arc + arp) - inter + 1e-9f;
            bool pred = (inter / denom) > 0.7f;
            u64 db = __ballot(pred);
            if (lane == 0) diagWS[r] = db;
        }
        __syncthreads();
        if (wave == 0) {
            u64 dreg = diagWS[lane];           // lane's own adjacency row (symmetric)
            u64 smv = partS[0];
#pragma unroll
            for (int q = 1; q < 16; ++q) smv |= partS[q];
            int rem = V - base;
            u64 vmask = (rem >= 64) ? ~0ULL : ((1ULL << rem) - 1ULL);
            u64 A = (~smv) & vmask;
            u64 below = (1ULL << lane) - 1ULL;
            bool inA = (A >> lane) & 1ULL;
            u64 S = A;
            while (true) {
                bool pred = inA && ((dreg & S & below) == 0ULL);
                u64 Snew = __ballot(pred);
                if (Snew == S) break;
                S = Snew;
            }
            int cnt = __popcll(S);
            int rem0 = NPOST - emitted;
            int rank = __popcll(S & below);
            bool kept = ((S >> lane) & 1ULL) && (rank < rem0);
            if (kept) {
                emS[emitted + rank]     = (unsigned)(base + lane);
                pboxAll[emitted + rank] = wboxS[buf][lane];
            }
            if (lane == 0) {
                int emadd = (cnt < rem0) ? cnt : rem0;
                stateS[0] = emitted + emadd;
                stateS[1] = (cnt >= rem0) ? 1 : 0;
            }
        } else if (wave == 15) {
            int nb = base + 64;
            if (nb < V && (w + 1) < NWORDS)
                wboxS[buf ^ 1][lane] = mobG[(size_t)img * NPAD + nb + lane];
        }
        __syncthreads();
        emitted = stateS[0];
        done = (stateS[1] != 0);
    }
    __syncthreads();
    for (int rr = tid; rr < NPOST; rr += 1024) {
        float* o = out + ((size_t)img * NPOST + rr) * 5;
        if (rr < emitted) {
            unsigned i = emS[rr];
            unsigned g = midxG[imgb + i];
            float4 cb = cbox[imgb + g];
            float sc = cscore[imgb + g];
            o[0] = cb.x; o[1] = cb.y; o[2] = cb.z; o[3] = cb.w; o[4] = sc;
        } else {
            o[0] = 0.f; o[1] = 0.f; o[2] = 0.f; o[3] = 0.f; o[4] = NEGF;
        }
    }
}

extern "C" void kernel_launch(void* const* d_in, const int* in_sizes, int n_in,
                              void* d_out, int out_size, void* d_ws, size_t ws_size,
                              hipStream_t stream) {
    Ptrs P;
    for (int l = 0; l < 5; ++l) {
        P.lg[l] = (const float*)d_in[2 * l];
        P.dl[l] = (const float*)d_in[2 * l + 1];
    }
    char* w = (char*)d_ws;
    size_t off = 0;
    auto alloc = [&](size_t bytes) -> void* {
        void* pp = (void*)(w + off);
        off = (off + bytes + 255) & ~(size_t)255;
        return pp;
    };
    unsigned* bcnt   = (unsigned*)alloc((size_t)NIMG * NSLOT * 4);
    u64* compS       = (u64*)alloc((size_t)NIMG * NSLOT * SCAP * 8);      // 3.01 MB
    unsigned* histFB = (unsigned*)alloc((size_t)NTASK * NB1 * 4);         // 2.6 MB, fallback only
    float*  cscore   = (float*)alloc((size_t)NTASK * K_TOP * 4);
    float4* cbox     = (float4*)alloc((size_t)NTASK * K_TOP * 16);
    float4* cobox    = (float4*)alloc((size_t)NTASK * K_TOP * 16);
    unsigned* cog    = (unsigned*)alloc((size_t)NTASK * K_TOP * 4);
    unsigned* vcnt   = (unsigned*)alloc(NTASK * 4);
    float4* mobG     = (float4*)alloc((size_t)NIMG * NPAD * 16);
    unsigned* midxG  = (unsigned*)alloc((size_t)NIMG * NCAND * 4);
    (void)in_sizes; (void)n_in; (void)out_size; (void)ws_size;

    kStage<<<dim3(NSLOT, NIMG), 1024, 0, stream>>>(P, compS, bcnt);
    kSortSelect<<<NTASK, 1024, 0, stream>>>(P, compS, bcnt, histFB,
                                            cscore, cbox, cobox, cog, vcnt);
    kMergeRank<<<NTASK, 1024, 0, stream>>>(cscore, cobox, cog, vcnt, mobG, midxG);
    kScan<<<NIMG, 1024, 0, stream>>>(mobG, midxG, cscore, cbox, vcnt,
                                     (float*)d_out);
}

// Round 31
// 61.549 us; speedup vs baseline: 1.2649x; 1.0076x over previous
//
#include <hip/hip_runtime.h>
#include <cstdint>
#include <cstddef>

#define NB1      16384      // 2^14 bins (fallback path only)
#define L1SHIFT  18
#define K_TOP    1000
#define NCAND    5000
#define NIMG     8
#define NLVL     5
#define NTASK    40
#define NPOST    300
#define NEGF     (-1e9f)
#define NWORDS   79         // ceil(5000/64)
#define NPAD     (NWORDS * 64)
#define NSLOT    23         // per-image slices: 16+4+1+1+1
#define SCAP     2048       // per-slice staged-candidate cap

typedef unsigned long long u64;

struct Ptrs {
    const float* lg[5];
    const float* dl[5];
};

__device__ __forceinline__ unsigned key_of(float f) {
    unsigned u = __float_as_uint(f);
    return (u & 0x80000000u) ? ~u : (u | 0x80000000u);
}

__device__ __forceinline__ void lvl_of_slot(int bx, int& lvl, int& lb, int& gx, int& m) {
    lvl = (bx < 16) ? 0 : (bx < 20) ? 1 : (bx < 21) ? 2 : (bx < 22) ? 3 : 4;
    const int S0[5] = {0, 16, 20, 21, 22};
    const int GX[5] = {16, 4, 1, 1, 1};
    const int MS[5] = {516096, 129024, 32256, 8064, 2016};
    lb = bx - S0[lvl];
    gx = GX[lvl];
    m  = MS[lvl];
}

// ---------------- pass 1: pure stream + fixed-threshold staging (no histogram) ----
// Tf = {2.75,2.3,1.7,0.9,-0.35}: staged/task ~{1538,1384,1437,1484,1284}, all
// >=10 sigma above K=1000 (cutoffs z={2.89,2.42,1.87,1.155,0.01}); kSortSelect
// verifies exactly by counts and falls back to a histogram select on mismatch.
__global__ __launch_bounds__(1024) void kStage(Ptrs p,
                                               u64* __restrict__ compS,
                                               unsigned* __restrict__ bcnt) {
    int lvl, lb, gx, m;
    lvl_of_slot(blockIdx.x, lvl, lb, gx, m);
    int img = blockIdx.y;
    size_t slice = (size_t)img * NSLOT + blockIdx.x;
    const float* lg = p.lg[lvl];
    const float TF5[5] = {2.75f, 2.3f, 1.7f, 0.9f, -0.35f};
    float Tf = TF5[lvl];
    __shared__ unsigned lcnt;
    int tid = threadIdx.x, lane = tid & 63;
    if (tid == 0) lcnt = 0u;
    __syncthreads();
    int m4 = m >> 2;
    int chunk4 = (m4 + gx - 1) / gx;
    int start4 = lb * chunk4;
    int end4   = min(start4 + chunk4, m4);
    const float4* src = (const float4*)(lg + (size_t)img * m);
    u64 below = (1ULL << lane) - 1ULL;
    for (int ib = start4; ib < end4; ib += 1024) {
        int i = ib + tid;
        bool inb = (i < end4);
        float4 v = inb ? src[i] : make_float4(0.f, 0.f, 0.f, 0.f);
        int j = i * 4;
        bool p0 = inb && (v.x > Tf);
        bool p1 = inb && (v.y > Tf);
        bool p2 = inb && (v.z > Tf);
        bool p3 = inb && (v.w > Tf);
        u64 m0 = __ballot(p0);
        u64 m1 = __ballot(p1);
        u64 m2 = __ballot(p2);
        u64 m3 = __ballot(p3);
        unsigned n0 = (unsigned)__popcll(m0), n1 = (unsigned)__popcll(m1);
        unsigned n2 = (unsigned)__popcll(m2), n3 = (unsigned)__popcll(m3);
        unsigned ntot = n0 + n1 + n2 + n3;
        unsigned base = 0;
        if (lane == 0 && ntot) base = atomicAdd(&lcnt, ntot);
        base = (unsigned)__shfl((int)base, 0, 64);
        if (p0) { unsigned q = base + (unsigned)__popcll(m0 & below);
                  if (q < SCAP) compS[slice * SCAP + q] = ((u64)key_of(v.x) << 32) | (unsigned)(~(unsigned)(j)); }
        if (p1) { unsigned q = base + n0 + (unsigned)__popcll(m1 & below);
                  if (q < SCAP) compS[slice * SCAP + q] = ((u64)key_of(v.y) << 32) | (unsigned)(~(unsigned)(j + 1)); }
        if (p2) { unsigned q = base + n0 + n1 + (unsigned)__popcll(m2 & below);
                  if (q < SCAP) compS[slice * SCAP + q] = ((u64)key_of(v.z) << 32) | (unsigned)(~(unsigned)(j + 2)); }
        if (p3) { unsigned q = base + n0 + n1 + n2 + (unsigned)__popcll(m3 & below);
                  if (q < SCAP) compS[slice * SCAP + q] = ((u64)key_of(v.w) << 32) | (unsigned)(~(unsigned)(j + 3)); }
    }
    __syncthreads();
    if (tid == 0) bcnt[slice] = lcnt;            // RAW count (cap checked later)
}

// ---------------- pass 2: count-verified gather + register bitonic, decode ------
// Thi = {2.97,2.5,1.95,1.25,0.15}: cS ~{768,801,825,852,888} <= 1024 (6-9 sigma)
// and cB ~{770,583,612,632,396} <= 1024 (>=6 sigma) -> 2048-network never runs.
// LDS bitonic exchanges ping-pong between two buffer pairs: 1 barrier/phase.
__global__ __launch_bounds__(1024) void kSortSelect(
        Ptrs p,
        const u64* __restrict__ compS,
        const unsigned* __restrict__ bcnt,
        unsigned* __restrict__ histFB,
        float* __restrict__ cscore,
        float4* __restrict__ cbox,
        float4* __restrict__ cobox,
        unsigned* __restrict__ cog,
        unsigned* __restrict__ vcnt) {
    int task = blockIdx.x;
    int img = task / NLVL, lvl = task % NLVL;
    int tid = threadIdx.x, lane = tid & 63, wv = tid >> 6;
    const int   MS5[5]    = {516096, 129024, 32256, 8064, 2016};
    const int   GW[5]     = {512, 256, 128, 64, 32};
    const float STRIDEF[5]= {4.f, 8.f, 16.f, 32.f, 64.f};
    const int   SIZEI[5]  = {32, 64, 128, 256, 512};
    const float THI5[5]   = {2.97f, 2.5f, 1.95f, 1.25f, 0.15f};   // sure/bnd split
    __shared__ u64 sure[1024];
    __shared__ u64 bnd[2048];
    __shared__ u64 su2[1024];           // ping-pong partners for LDS phases
    __shared__ u64 bn2[1024];
    __shared__ unsigned sblkF[256];
    __shared__ int tmpF[8];
    __shared__ unsigned cS, cB;
    __shared__ unsigned soff[17];
    __shared__ int wTot[16];
    __shared__ int fbS;
    unsigned KH = key_of(THI5[lvl]);
    if (tid == 0) { cS = 0u; cB = 0u; }
    sure[tid] = 0ULL;
    bnd[tid] = 0ULL; bnd[tid + 1024] = 0ULL;
    if (tid < 17) soff[tid] = 0u;
    if (tid == 0) fbS = 0;
    __syncthreads();
    const int S0[5] = {0, 16, 20, 21, 22};
    const int NS[5] = {16, 4, 1, 1, 1};
    int s0 = S0[lvl], ns = NS[lvl];
    if (tid < ns) {
        unsigned raw = bcnt[(size_t)img * NSLOT + s0 + tid];
        if (raw > SCAP) atomicOr((unsigned*)&fbS, 1u);   // slice capped -> fallback
        soff[tid + 1] = min(raw, (unsigned)SCAP);
    }
    __syncthreads();
    if (tid == 0)
        for (int s = 1; s <= 16; ++s) soff[s] += soff[s - 1];
    __syncthreads();
    int tot = (int)soff[ns];
    u64 below = (1ULL << lane) - 1ULL;
    for (int ib = 0; ib < tot; ib += 1024) {
        int idx = ib + tid;
        bool inb = (idx < tot);
        u64 c = 0ULL;
        if (inb) {
            int s = 0;
            while ((int)soff[s + 1] <= idx) ++s;     // <=16 LDS reads
            c = compS[((size_t)img * NSLOT + s0 + s) * SCAP + (idx - (int)soff[s])];
        }
        bool pS = inb && ((unsigned)(c >> 32) > KH);   // v > Tf_hi
        bool pB = inb && !pS;                          // Tf < v <= Tf_hi
        u64 mS = __ballot(pS);
        u64 mB = __ballot(pB);
        unsigned bS = 0, bB = 0;
        if (lane == 0) {
            if (mS) bS = atomicAdd(&cS, (unsigned)__popcll(mS));
            if (mB) bB = atomicAdd(&cB, (unsigned)__popcll(mB));
        }
        bS = (unsigned)__shfl((int)bS, 0, 64);
        bB = (unsigned)__shfl((int)bB, 0, 64);
        if (pS) { unsigned q = bS + (unsigned)__popcll(mS & below); if (q < 1024u) sure[q] = c; }
        if (pB) { unsigned q = bB + (unsigned)__popcll(mB & below); if (q < 2048u) bnd[q] = c; }
    }
    __syncthreads();
    // ---- exact verification (pure counts) ----
    if (tid == 0) {
        if (cS > 1024u || cB > 2048u || (cS + cB) < (unsigned)K_TOP) fbS = 1;
    }
    __syncthreads();
    // ---- fallback: histogram select over raw logits, hist in GLOBAL scratch ----
    if (fbS) {
        int mm = MS5[lvl];
        int mm4 = mm >> 2;
        const float4* s4 = (const float4*)(p.lg[lvl] + (size_t)img * mm);
        unsigned* h = histFB + (size_t)task * NB1;
        for (int i = tid; i < NB1; i += 1024) h[i] = 0u;
        __syncthreads();
        for (int i = tid; i < mm4; i += 1024) {
            float4 v = s4[i];
            atomicAdd(&h[key_of(v.x) >> L1SHIFT], 1u);
            atomicAdd(&h[key_of(v.y) >> L1SHIFT], 1u);
            atomicAdd(&h[key_of(v.z) >> L1SHIFT], 1u);
            atomicAdd(&h[key_of(v.w) >> L1SHIFT], 1u);
        }
        __syncthreads();
        if (tid < 256) {
            unsigned coarse = 0;
            for (int ii = 0; ii < 64; ++ii) coarse += h[tid * 64 + ii];
            sblkF[tid] = coarse;
        }
        __syncthreads();
        unsigned SSv = 0;
        if (tid < 256) {
            SSv = sblkF[tid];
            for (int d = 1; d < 64; d <<= 1) {
                unsigned o = __shfl_down(SSv, d, 64);
                if (lane < 64 - d) SSv += o;
            }
            unsigned wtot = __shfl(SSv, 0, 64);
            if (lane == 0) tmpF[4 + wv] = (int)wtot;
        }
        __syncthreads();
        if (tid < 256) {
            unsigned add = 0;
            for (int w2 = wv + 1; w2 < 4; ++w2) add += (unsigned)tmpF[4 + w2];
            SSv += add;
            bool pred = (SSv >= (unsigned)K_TOP);
            u64 mk = __ballot(pred);
            if (lane == 0)
                tmpF[wv] = mk ? (wv * 64 + (63 - __builtin_clzll(mk))) : -1;
        }
        __syncthreads();
        int tb = max(max(tmpF[0], tmpF[1]), max(tmpF[2], tmpF[3]));
        __syncthreads();
        if (tid == 0) {
            unsigned above = 0;
            for (int b2 = tb + 1; b2 < 256; ++b2) above += sblkF[b2];
            unsigned rem = (unsigned)K_TOP - above;
            unsigned suf = 0;
            int pfx = tb * 64;
            for (int u2 = 63; u2 >= 0; --u2) {
                suf += h[tb * 64 + u2];
                if (suf >= rem) { pfx = tb * 64 + u2; break; }
            }
            tmpF[0] = pfx;
        }
        __syncthreads();
        unsigned pfx = (unsigned)tmpF[0];
        if (tid == 0) { cS = 0u; cB = 0u; }
        sure[tid] = 0ULL;
        bnd[tid] = 0ULL; bnd[tid + 1024] = 0ULL;
        __syncthreads();
        for (int ib = 0; ib < mm4; ib += 1024) {
            int i = ib + tid;
            bool inb = (i < mm4);
            float4 v = inb ? s4[i] : make_float4(0.f, 0.f, 0.f, 0.f);
            int j = i * 4;
            unsigned kk[4] = { key_of(v.x), key_of(v.y), key_of(v.z), key_of(v.w) };
#pragma unroll
            for (int e = 0; e < 4; ++e) {
                unsigned bin = kk[e] >> L1SHIFT;
                bool pS2 = inb && (bin > pfx);
                bool pB2 = inb && (bin == pfx);
                u64 mS2 = __ballot(pS2);
                u64 mB2 = __ballot(pB2);
                unsigned bS2 = 0, bB2 = 0;
                if (lane == 0) {
                    if (mS2) bS2 = atomicAdd(&cS, (unsigned)__popcll(mS2));
                    if (mB2) bB2 = atomicAdd(&cB, (unsigned)__popcll(mB2));
                }
                bS2 = (unsigned)__shfl((int)bS2, 0, 64);
                bB2 = (unsigned)__shfl((int)bB2, 0, 64);
                u64 cc = ((u64)kk[e] << 32) | (unsigned)(~(unsigned)(j + e));
                if (pS2) { unsigned q = bS2 + (unsigned)__popcll(mS2 & below); if (q < 1024u) sure[q] = cc; }
                if (pB2) { unsigned q = bB2 + (unsigned)__popcll(mB2 & below); if (q < 2048u) bnd[q] = cc; }
            }
        }
        __syncthreads();
    }
    unsigned S = cS;
    unsigned B = cB;
    // register bitonic (desc); shfl for j<64; ping-pong LDS for j>=64 (1 barrier/phase)
    u64 xs = sure[tid], xb = bnd[tid];      // own-element reads: no barrier needed
    int pp = 0;
    for (int k = 2; k <= 1024; k <<= 1) {
        for (int j = k >> 1; j > 0; j >>= 1) {
            bool up   = ((tid & k) == 0);
            bool iLow = ((tid & j) == 0);
            u64 ys, yb;
            if (j >= 64) {
                u64* sbuf = pp ? su2 : sure;
                u64* bbuf = pp ? bn2 : bnd;
                sbuf[tid] = xs; bbuf[tid] = xb;
                __syncthreads();
                ys = sbuf[tid ^ j]; yb = bbuf[tid ^ j];
                pp ^= 1;                     // next LDS phase uses other buffers
            } else {
                ys = __shfl_xor(xs, j, 64);
                yb = __shfl_xor(xb, j, 64);
            }
            bool takeMax = (iLow == up);
            xs = takeMax ? ((xs > ys) ? xs : ys) : ((xs < ys) ? xs : ys);
            xb = takeMax ? ((xb > yb) ? xb : yb) : ((xb < yb) ? xb : yb);
        }
    }
    sure[tid] = xs; bnd[tid] = xb;          // writes own element; no read clash
    __syncthreads();
    if (B > 1024) {    // correctness fallback only; thresholds keep B <= 1024
        for (int k = 2; k <= 2048; k <<= 1)
            for (int j = k >> 1; j > 0; j >>= 1) {
                int i = ((tid & ~(j - 1)) << 1) | (tid & (j - 1));
                int ppi = i | j;
                u64 A = bnd[i], Bv = bnd[ppi];
                bool up = ((i & k) == 0);
                if (up ? (A < Bv) : (A > Bv)) { bnd[i] = Bv; bnd[ppi] = A; }
                __syncthreads();
            }
    }
    int r = tid;
    u64 c = 0ULL;
    if (r < K_TOP) c = (r < (int)S) ? sure[r] : ((r - (int)S < (int)B) ? bnd[r - (int)S] : 0ULL);

    float sm = NEGF, x0 = 0.f, y0 = 0.f, x1 = 0.f, y1 = 0.f;
    float b0 = 0.f, b1 = 0.f, b2 = 0.f, b3 = 0.f;
    bool valid = false;
    if (r < K_TOP && c != 0ULL) {
        int idx = (int)(~(unsigned)c);
        int m = MS5[lvl];
        if ((unsigned)idx >= (unsigned)m) idx = 0;   // safety (never expected)
        const float* lg = p.lg[lvl];
        const float* dl = p.dl[lvl];
        float score = lg[(size_t)img * m + idx];
        int a   = idx % 3;
        int loc = idx / 3;
        int gw  = GW[lvl];
        int x = loc % gw, y = loc / gw;
        double ssz = (double)SIZEI[lvl];
        double arr = (a == 0) ? 0.5 : ((a == 1) ? 1.0 : 2.0);
        double wd = sqrt(ssz * ssz / arr);
        double hd = arr * wd;
        float sx = (float)x * STRIDEF[lvl];
        float sy = (float)y * STRIDEF[lvl];
        float a0 = sx + (float)(-wd * 0.5);
        float a1 = sy + (float)(-hd * 0.5);
        float a2 = sx + (float)( wd * 0.5);
        float a3 = sy + (float)( hd * 0.5);
        float aw = a2 - a0, ah = a3 - a1;
        float acx = a0 + 0.5f * aw, acy = a1 + 0.5f * ah;
        size_t db = ((size_t)img * m + idx) * 4;
        float dx = dl[db], dy = dl[db + 1], dwv = dl[db + 2], dhv = dl[db + 3];
        const float CL = 4.135166556742356f;   // log(1000/16)
        float pw = expf(fminf(dwv, CL)) * aw;
        float ph = expf(fminf(dhv, CL)) * ah;
        float pcx = dx * aw + acx;
        float pcy = dy * ah + acy;
        x0 = pcx - 0.5f * pw; y0 = pcy - 0.5f * ph;
        x1 = pcx + 0.5f * pw; y1 = pcy + 0.5f * ph;
        x0 = fminf(fmaxf(x0, 0.f), 2048.f);
        x1 = fminf(fmaxf(x1, 0.f), 2048.f);
        y0 = fminf(fmaxf(y0, 0.f), 1344.f);
        y1 = fminf(fmaxf(y1, 0.f), 1344.f);
        bool keep = ((x1 - x0) > 0.f) && ((y1 - y0) > 0.f);
        valid = keep;
        sm = score;
        float off = (float)lvl * 2049.0f;
        b0 = x0 + off; b1 = y0 + off; b2 = x1 + off; b3 = y1 + off;
    }
    // ballot-based valid compaction (exclusive pos, total)
    u64 vm = __ballot(valid);
    int lanePre = (int)__popcll(vm & ((1ULL << lane) - 1ULL));
    if (lane == 0) wTot[wv] = (int)__popcll(vm);
    __syncthreads();
    int offset = 0, total = 0;
    for (int w2 = 0; w2 < 16; ++w2) {
        int t2 = wTot[w2];
        total += t2;
        if (w2 < wv) offset += t2;
    }
    int pos = offset + lanePre;
    if (valid) {
        int ci = img * NCAND + lvl * K_TOP + pos;
        cscore[ci] = sm;
        cbox[ci]   = make_float4(x0, y0, x1, y1);
        cobox[ci]  = make_float4(b0, b1, b2, b3);
        cog[ci]    = (unsigned)r;
    }
    if (tid == 0) vcnt[task] = (unsigned)total;
}

// ---------------- pass 3: rank-merge, 1 block per (img,lvl), scatter to global ----
__global__ __launch_bounds__(1024) void kMergeRank(
        const float* __restrict__ cscore,
        const float4* __restrict__ cobox,
        const unsigned* __restrict__ cog,
        const unsigned* __restrict__ vcnt,
        float4* __restrict__ mobG,
        unsigned* __restrict__ midxG) {
    int task = blockIdx.x;
    int img = task / NLVL, lvl = task % NLVL;
    int tid = threadIdx.x;
    const int imgb = img * NCAND;
    __shared__ u64 compO[4 * K_TOP];    // other 4 levels' composites (32 KB)
    __shared__ int LSs[NLVL];
    if (tid < NLVL) LSs[tid] = (int)vcnt[img * NLVL + tid];
    __syncthreads();
    for (int idx = tid; idx < 4 * K_TOP; idx += 1024) {
        int q = idx / K_TOP, gl2 = idx - q * K_TOP;
        int l2 = q + (q >= lvl ? 1 : 0);
        u64 c = 0ULL;
        if (gl2 < LSs[l2]) {
            int g2 = l2 * K_TOP + gl2;
            unsigned og = (unsigned)(l2 * K_TOP) + cog[imgb + g2];
            c = ((u64)key_of(cscore[imgb + g2]) << 32) | (unsigned)(~og);
        }
        compO[idx] = c;
    }
    __syncthreads();
    int gl = tid;
    if (gl < LSs[lvl]) {
        int g = lvl * K_TOP + gl;
        float4 pref = cobox[imgb + g];             // overlap HBM with LDS searches
        unsigned og = (unsigned)(lvl * K_TOP) + cog[imgb + g];
        u64 c = ((u64)key_of(cscore[imgb + g]) << 32) | (unsigned)(~og);
        int l0 = 0, h0 = LSs[0 + (0 >= lvl ? 1 : 0)];
        int l1 = 0, h1 = LSs[1 + (1 >= lvl ? 1 : 0)];
        int l2 = 0, h2 = LSs[2 + (2 >= lvl ? 1 : 0)];
        int l3 = 0, h3 = LSs[3 + (3 >= lvl ? 1 : 0)];
#pragma unroll
        for (int step = 0; step < 10; ++step) {    // lists <= 1000 -> 10 steps
            if (l0 < h0) { int m0 = (l0 + h0) >> 1; if (compO[0 * K_TOP + m0] > c) l0 = m0 + 1; else h0 = m0; }
            if (l1 < h1) { int m1 = (l1 + h1) >> 1; if (compO[1 * K_TOP + m1] > c) l1 = m1 + 1; else h1 = m1; }
            if (l2 < h2) { int m2 = (l2 + h2) >> 1; if (compO[2 * K_TOP + m2] > c) l2 = m2 + 1; else h2 = m2; }
            if (l3 < h3) { int m3 = (l3 + h3) >> 1; if (compO[3 * K_TOP + m3] > c) l3 = m3 + 1; else h3 = m3; }
        }
        int pos = gl + l0 + l1 + l2 + l3;
        mobG[(size_t)img * NPAD + pos] = pref;
        midxG[imgb + pos] = (unsigned)g;
    }
}

// ---------------- pass 4: greedy scan; within-word selection via MIS fixpoint ----------------
__global__ __launch_bounds__(1024) void kScan(
        const float4* __restrict__ mobG,
        const unsigned* __restrict__ midxG,
        const float* __restrict__ cscore,
        const float4* __restrict__ cbox,
        const unsigned* __restrict__ vcnt,
        float* __restrict__ out) {
    int img = blockIdx.x;
    int tid = threadIdx.x;
    int lane = tid & 63;
    int wave = tid >> 6;
    __shared__ float4 wboxS[2][64];     // double buffer (prefetch during serial)
    __shared__ u64    diagWS[64];
    __shared__ u64    partS[16];
    __shared__ float4 pboxAll[NPOST];
    __shared__ unsigned emS[NPOST];
    __shared__ int stateS[2];           // {emitted, done}
    const int imgb = img * NCAND;

    int V = 0;
    for (int l = 0; l < NLVL; ++l) V += (int)vcnt[img * NLVL + l];

    if (tid < 64 && V > 0) wboxS[0][tid] = mobG[(size_t)img * NPAD + tid];
    __syncthreads();

    int emitted = 0;
    bool done = (V == 0);
    for (int w = 0; w < NWORDS && !done; ++w) {
        int base = w * 64;
        if (base >= V) break;
        int buf = w & 1;
        float4 bc = wboxS[buf][lane];
        float  arc = (bc.z - bc.x) * (bc.w - bc.y);
        bool supp = false;
        for (int t = wave; t < emitted; t += 16) {
            float4 bp = pboxAll[t];
            float arp = (bp.z - bp.x) * (bp.w - bp.y);
            float ltx = fmaxf(bc.x, bp.x), lty = fmaxf(bc.y, bp.y);
            float rbx = fminf(bc.z, bp.z), rby = fminf(bc.w, bp.w);
            float wx = fmaxf(rbx - ltx, 0.f), wy = fmaxf(rby - lty, 0.f);
            float inter = wx * wy;
            float denom = (arc + arp) - inter + 1e-9f;
            supp |= (inter / denom) > 0.7f;
        }
        u64 sb = __ballot(supp);
        if (lane == 0) partS[wave] = sb;
#pragma unroll
        for (int rr = 0; rr < 4; ++rr) {
            int r = wave * 4 + rr;
            float4 bp = wboxS[buf][r];
            float arp = (bp.z - bp.x) * (bp.w - bp.y);
            float ltx = fmaxf(bc.x, bp.x), lty = fmaxf(bc.y, bp.y);
            float rbx = fminf(bc.z, bp.z), rby = fminf(bc.w, bp.w);
            float wx = fmaxf(rbx - ltx, 0.f), wy = fmaxf(rby - lty, 0.f);
            float inter = wx * wy;
            float denom = (arc + arp) - inter + 1e-9f;
            bool pred = (inter / denom) > 0.7f;
            u64 db = __ballot(pred);
            if (lane == 0) diagWS[r] = db;
        }
        __syncthreads();
        if (wave == 0) {
            u64 dreg = diagWS[lane];           // lane's own adjacency row (symmetric)
            u64 smv = partS[0];
#pragma unroll
            for (int q = 1; q < 16; ++q) smv |= partS[q];
            int rem = V - base;
            u64 vmask = (rem >= 64) ? ~0ULL : ((1ULL << rem) - 1ULL);
            u64 A = (~smv) & vmask;
            u64 below = (1ULL << lane) - 1ULL;
            bool inA = (A >> lane) & 1ULL;
            u64 S = A;
            while (true) {
                bool pred = inA && ((dreg & S & below) == 0ULL);
                u64 Snew = __ballot(pred);
                if (Snew == S) break;
                S = Snew;
            }
            int cnt = __popcll(S);
            int rem0 = NPOST - emitted;
            int rank = __popcll(S & below);
            bool kept = ((S >> lane) & 1ULL) && (rank < rem0);
            if (kept) {
                emS[emitted + rank]     = (unsigned)(base + lane);
                pboxAll[emitted + rank] = wboxS[buf][lane];
            }
            if (lane == 0) {
                int emadd = (cnt < rem0) ? cnt : rem0;
                stateS[0] = emitted + emadd;
                stateS[1] = (cnt >= rem0) ? 1 : 0;
            }
        } else if (wave == 15) {
            int nb = base + 64;
            if (nb < V && (w + 1) < NWORDS)
                wboxS[buf ^ 1][lane] = mobG[(size_t)img * NPAD + nb + lane];
        }
        __syncthreads();
        emitted = stateS[0];
        done = (stateS[1] != 0);
    }
    __syncthreads();
    for (int rr = tid; rr < NPOST; rr += 1024) {
        float* o = out + ((size_t)img * NPOST + rr) * 5;
        if (rr < emitted) {
            unsigned i = emS[rr];
            unsigned g = midxG[imgb + i];
            float4 cb = cbox[imgb + g];
            float sc = cscore[imgb + g];
            o[0] = cb.x; o[1] = cb.y; o[2] = cb.z; o[3] = cb.w; o[4] = sc;
        } else {
            o[0] = 0.f; o[1] = 0.f; o[2] = 0.f; o[3] = 0.f; o[4] = NEGF;
        }
    }
}

extern "C" void kernel_launch(void* const* d_in, const int* in_sizes, int n_in,
                              void* d_out, int out_size, void* d_ws, size_t ws_size,
                              hipStream_t stream) {
    Ptrs P;
    for (int l = 0; l < 5; ++l) {
        P.lg[l] = (const float*)d_in[2 * l];
        P.dl[l] = (const float*)d_in[2 * l + 1];
    }
    char* w = (char*)d_ws;
    size_t off = 0;
    auto alloc = [&](size_t bytes) -> void* {
        void* pp = (void*)(w + off);
        off = (off + bytes + 255) & ~(size_t)255;
        return pp;
    };
    unsigned* bcnt   = (unsigned*)alloc((size_t)NIMG * NSLOT * 4);
    u64* compS       = (u64*)alloc((size_t)NIMG * NSLOT * SCAP * 8);      // 3.01 MB
    unsigned* histFB = (unsigned*)alloc((size_t)NTASK * NB1 * 4);         // 2.6 MB, fallback only
    float*  cscore   = (float*)alloc((size_t)NTASK * K_TOP * 4);
    float4* cbox     = (float4*)alloc((size_t)NTASK * K_TOP * 16);
    float4* cobox    = (float4*)alloc((size_t)NTASK * K_TOP * 16);
    unsigned* cog    = (unsigned*)alloc((size_t)NTASK * K_TOP * 4);
    unsigned* vcnt   = (unsigned*)alloc(NTASK * 4);
    float4* mobG     = (float4*)alloc((size_t)NIMG * NPAD * 16);
    unsigned* midxG  = (unsigned*)alloc((size_t)NIMG * NCAND * 4);
    (void)in_sizes; (void)n_in; (void)out_size; (void)ws_size;

    kStage<<<dim3(NSLOT, NIMG), 1024, 0, stream>>>(P, compS, bcnt);
    kSortSelect<<<NTASK, 1024, 0, stream>>>(P, compS, bcnt, histFB,
                                            cscore, cbox, cobox, cog, vcnt);
    kMergeRank<<<NTASK, 1024, 0, stream>>>(cscore, cobox, cog, vcnt, mobG, midxG);
    kScan<<<NIMG, 1024, 0, stream>>>(mobG, midxG, cscore, cbox, vcnt,
                                     (float*)d_out);
}